// Round 17
// baseline (272.953 us; speedup 1.0000x reference)
//
#include <hip/hip_runtime.h>
#include <stdint.h>
#include <stddef.h>

// ---------- types ----------
typedef _Float16 half_t;
typedef half_t half8  __attribute__((ext_vector_type(8)));
typedef half_t half4v __attribute__((ext_vector_type(4)));
typedef float  f32x4  __attribute__((ext_vector_type(4)));

__device__ __forceinline__ float fast_sigmoid(float x) {
    float e = __builtin_amdgcn_exp2f(-1.44269504f * x);
    return __builtin_amdgcn_rcpf(1.0f + e);
}
__device__ __forceinline__ float fast_tanh(float x) {
    float e = __builtin_amdgcn_exp2f(2.88539008f * x);
    return 1.0f - 2.0f * __builtin_amdgcn_rcpf(1.0f + e);
}

// ---------------------------------------------------------------------------
// Prep: W [1024][256] f32 row-major -> MFMA-B fragment order, f16.
// Bijection (contiguous k): lane l, elem e of tile (T,kt) holds
//   B[k = kt*32 + (l>>4)*8 + e, j = T*16 + (l&15)].
// A-fragments from LDS use the SAME mapping (validated R1-R16, absmax 2e-3).
// ---------------------------------------------------------------------------
__global__ __launch_bounds__(64) void shuffle_w_kernel(
    const float* __restrict__ W, half_t* __restrict__ out)
{
    const int blk = blockIdx.x;         // 512 = 64 T * 8 kt
    const int T = blk >> 3, kt = blk & 7;
    const int l = threadIdx.x;
    const int j = T * 16 + (l & 15);
    const int k0 = kt * 32 + ((l >> 4) << 3);
    half8 v;
#pragma unroll
    for (int e = 0; e < 8; ++e) v[e] = (half_t)W[j * 256 + k0 + e];
    *reinterpret_cast<half8*>(out + (size_t)(blk * 64 + l) * 8) = v;
}

// ---------------------------------------------------------------------------
// 1-gate-pair (2 N-tile) GEMM pass with B double-buffer. kt loop PINNED
// (unroll 1 + sched_barrier per window) -- the R4-R16 proven anti-spill
// structure. Small state: acc 32 + b dbuf 16 + a 16 + addr ~12 in flight.
// ---------------------------------------------------------------------------
__device__ __forceinline__ void gemm_pass(
    f32x4* acc, const half_t* __restrict__ lhx,
    const half_t* Ws, int T0, int T1, int lm, int lg, int l)
{
    asm volatile("" : "+v"(Ws));   // anti-LICM: recompute bp per call
    const half_t* bp0 = Ws + (size_t)((T0 * 8) * 64 + l) * 8;
    const half_t* bp1 = Ws + (size_t)((T1 * 8) * 64 + l) * 8;
    half8 bA[2], bB[2];
    bA[0] = *reinterpret_cast<const half8*>(bp0);
    bA[1] = *reinterpret_cast<const half8*>(bp1);

#pragma unroll 1
    for (int kt2 = 0; kt2 < 4; ++kt2) {
        const int kt = kt2 * 2;
        // prefetch b(kt+1); MFMA(kt) with bA
        bB[0] = *reinterpret_cast<const half8*>(bp0 + (kt + 1) * 512);
        bB[1] = *reinterpret_cast<const half8*>(bp1 + (kt + 1) * 512);
        {
            half8 a[4];
#pragma unroll
            for (int mt = 0; mt < 4; ++mt) {
                const int p = mt * 16 + lm;
                const int k = (kt * 32 + lg * 8) ^ ((p & 7) << 4);
                a[mt] = *reinterpret_cast<const half8*>(&lhx[p * 256 + k]);
            }
#pragma unroll
            for (int n = 0; n < 2; ++n)
#pragma unroll
                for (int mt = 0; mt < 4; ++mt)
                    acc[mt * 2 + n] = __builtin_amdgcn_mfma_f32_16x16x32_f16(
                        a[mt], bA[n], acc[mt * 2 + n], 0, 0, 0);
        }
        __builtin_amdgcn_sched_barrier(0);
        // prefetch b(kt+2) (wrap harmless); MFMA(kt+1) with bB
        bA[0] = *reinterpret_cast<const half8*>(bp0 + ((kt + 2) & 7) * 512);
        bA[1] = *reinterpret_cast<const half8*>(bp1 + ((kt + 2) & 7) * 512);
        {
            half8 a[4];
#pragma unroll
            for (int mt = 0; mt < 4; ++mt) {
                const int p = mt * 16 + lm;
                const int k = ((kt + 1) * 32 + lg * 8) ^ ((p & 7) << 4);
                a[mt] = *reinterpret_cast<const half8*>(&lhx[p * 256 + k]);
            }
#pragma unroll
            for (int n = 0; n < 2; ++n)
#pragma unroll
                for (int mt = 0; mt < 4; ++mt)
                    acc[mt * 2 + n] = __builtin_amdgcn_mfma_f32_16x16x32_f16(
                        a[mt], bB[n], acc[mt * 2 + n], 0, 0, 0);
        }
        __builtin_amdgcn_sched_barrier(0);
    }
}

// ---------------------------------------------------------------------------
// Persistent LSTM: block = 64 rows x 16 steps, 16 waves (1024 threads),
// 1 block/CU (160 KB LDS) -> 4 waves/SIMD. R16 post-mortem: at 2 waves/SIMD
// ~16K cyc/step had neither pipe issuing; doubling TLP fills the stalls at
// CONSTANT per-CU W traffic (unlike R13's 2-block variant).
// Wave w owns h-cols [w*16, w*16+16). Pass A=(f,o) tiles {16+w, 48+w};
// pass B=(i,g) tiles {w, 32+w}. Per-wave state: acc[8]=32, b dbuf 16,
// a 16, cxr 16, og 8, addr ~20 => ~108 <= 128 unified (4 waves/SIMD).
// R2-R5 failed this wave count at ~83 arch demand WITHOUT the toolkit
// (pinned windows, chunked init, anti-LICM); canary = WRITE_SIZE.
// LDS: hx 32 KB (XOR-swizzled) + xp 128 KB = 160 KB.
// ---------------------------------------------------------------------------
__global__ __launch_bounds__(1024)
void lstm_kernel(
    const float* __restrict__ x,      // [8][256][1600]
    const float* __restrict__ hx0,    // [12800][256]
    const float* __restrict__ cx0,    // [12800][256]
    const float* __restrict__ b_ih,   // [1024]
    const float* __restrict__ b_hh,   // [1024]
    const float* __restrict__ W_lin,  // [2][256]
    const float* __restrict__ b_lin,  // [2]
    const half_t* __restrict__ Wih_s, // shuffled f16
    const half_t* __restrict__ Whh_s, // shuffled f16
    float* __restrict__ out)          // [12800][16][2]
{
    __shared__ __align__(16) half_t lds_hx[64 * 256];         // 32 KB
    __shared__ __align__(16) half_t lds_xp[16 * 16 * 64 * 4]; // 128 KB

    const int tid = threadIdx.x;
    const int w  = tid >> 6;   // wave 0..15 owns h-cols [w*16, w*16+16)
    const int l  = tid & 63;
    const int lm = l & 15;
    const int lg = l >> 4;

    const int row0 = blockIdx.x * 64;     // 200 blocks * 64 rows
    const int bb_  = row0 / 1600;
    const int p0   = row0 % 1600;

    // ---- stage x tile into lds_hx, f16 swizzled (coalesced on p) ----
    {
        const float* xin = x + (size_t)bb_ * 409600 + p0;   // x[b][c][p0+p]
        for (int it = 0; it < 16; ++it) {
            int idx = it * 1024 + tid;
            int p = idx & 63, c = idx >> 6;
            lds_hx[p * 256 + (c ^ ((p & 7) << 4))] = (half_t)xin[c * 1600 + p];
        }
    }
    __syncthreads();

    f32x4 acc[8];

    // ---- phase 0: x_proj = x @ W_ih^T + b_ih + b_hh, 2 passes -> LDS ----
#pragma unroll 1
    for (int pass = 0; pass < 2; ++pass) {
        const int T0 = (pass ? 0 : 16) + w;   // pass0: f ; pass1: i
        const int T1 = (pass ? 32 : 48) + w;  // pass0: o ; pass1: g
#pragma unroll
        for (int n = 0; n < 2; ++n) {
            int col = (n ? T1 : T0) * 16 + lm;
            float bias = b_ih[col] + b_hh[col];
#pragma unroll
            for (int mt = 0; mt < 4; ++mt)
                acc[mt * 2 + n] = (f32x4){bias, bias, bias, bias};
        }
        gemm_pass(acc, lds_hx, Wih_s, T0, T1, lm, lg, l);
#pragma unroll
        for (int f = 0; f < 8; ++f) {
            half4v xv;
#pragma unroll
            for (int r = 0; r < 4; ++r) xv[r] = (half_t)acc[f][r];
            *reinterpret_cast<half4v*>(
                &lds_xp[((w * 16 + pass * 8 + f) * 64 + l) * 4]) = xv;
        }
    }
    __syncthreads();   // x tile fully consumed, xp written

    // ---- stage h0 into lds_hx (coalesced on c); cx into registers ----
    {
        const float* hin = hx0 + (size_t)row0 * 256;
        for (int it = 0; it < 16; ++it) {
            int idx = it * 1024 + tid;
            int c = idx & 255, p = idx >> 8;
            lds_hx[p * 256 + (c ^ ((p & 7) << 4))] = (half_t)hin[p * 256 + c];
        }
    }
    float cxr[16];
#pragma unroll
    for (int mt = 0; mt < 4; ++mt)
#pragma unroll
        for (int r = 0; r < 4; ++r) {
            int p = mt * 16 + lg * 4 + r;
            int c = w * 16 + lm;
            cxr[mt * 4 + r] = cx0[(size_t)(row0 + p) * 256 + c];
        }
    const float blin0 = b_lin[0], blin1 = b_lin[1];
    const int ph = tid >> 4;          // head: row 0..63
    const int ho = (tid >> 3) & 1;    // head: output 0..1
    const int hq = tid & 7;           // head: eighth of 256 h-cols
    __syncthreads();

    // ---------------- 16 recurrent steps ----------------
#pragma unroll 1
    for (int t = 0; t < 16; ++t) {
        half4v og[4];   // o-gate preactivations, f16 (R5-validated)

        // ---- pass A: gates (f,o); acc init CHUNKED (4 frags/fence) ----
#pragma unroll
        for (int fc = 0; fc < 8; fc += 4) {
#pragma unroll
            for (int f = fc; f < fc + 4; ++f) {
                half4v u = *reinterpret_cast<const half4v*>(
                    &lds_xp[((w * 16 + f) * 64 + l) * 4]);
#pragma unroll
                for (int r = 0; r < 4; ++r) acc[f][r] = (float)u[r];
            }
            __builtin_amdgcn_sched_barrier(0);
        }
        gemm_pass(acc, lds_hx, Whh_s, 16 + w, 48 + w, lm, lg, l);

        // epiA: fold sig(f) into cxr, stash o-preact f16
#pragma unroll
        for (int mt = 0; mt < 4; ++mt)
#pragma unroll
            for (int r = 0; r < 4; ++r) {
                float fv = acc[mt * 2 + 0][r];
                float ov = acc[mt * 2 + 1][r];
                cxr[mt * 4 + r] *= fast_sigmoid(fv);
                og[mt][r] = (half_t)ov;
            }
        __builtin_amdgcn_sched_barrier(0);

        // ---- pass B: gates (i,g); acc init CHUNKED ----
#pragma unroll
        for (int fc = 0; fc < 8; fc += 4) {
#pragma unroll
            for (int f = fc; f < fc + 4; ++f) {
                half4v u = *reinterpret_cast<const half4v*>(
                    &lds_xp[((w * 16 + 8 + f) * 64 + l) * 4]);
#pragma unroll
                for (int r = 0; r < 4; ++r) acc[f][r] = (float)u[r];
            }
            __builtin_amdgcn_sched_barrier(0);
        }
        gemm_pass(acc, lds_hx, Whh_s, w, 32 + w, lm, lg, l);

        __syncthreads();   // all waves finished reading lds_hx(t)

        // epiB: cell update; write hx(t+1) into lds_hx (f16, swizzled)
#pragma unroll
        for (int mt = 0; mt < 4; ++mt)
#pragma unroll
            for (int r = 0; r < 4; ++r) {
                float iv = acc[mt * 2 + 0][r];
                float gv = acc[mt * 2 + 1][r];
                float cxn = cxr[mt * 4 + r] + fast_sigmoid(iv) * fast_tanh(gv);
                cxr[mt * 4 + r] = cxn;
                float so = fast_sigmoid((float)og[mt][r]);
                float h = so * fast_tanh(cxn);
                int p  = mt * 16 + lg * 4 + r;
                int cc = w * 16 + lm;
                lds_hx[p * 256 + (cc ^ ((p & 7) << 4))] = (half_t)h;
            }
        __syncthreads();   // hx(t+1) visible to all

        // head: y = leaky_relu(hx) @ W_lin^T + b_lin -> [n][t][o]
        {
            const float* wl = W_lin + ho * 256 + hq * 32;
            asm volatile("" : "+v"(wl));     // defeat W_lin LICM
            float s = 0.0f;
#pragma unroll 2
            for (int cb = 0; cb < 8; ++cb) {
                int c0 = hq * 32 + cb * 4;
                half4v u = *reinterpret_cast<const half4v*>(
                    &lds_hx[ph * 256 + (c0 ^ ((ph & 7) << 4))]);
                float4 wv = *reinterpret_cast<const float4*>(wl + cb * 4);
                float h0 = (float)u[0], h1 = (float)u[1];
                float h2 = (float)u[2], h3 = (float)u[3];
                s += fmaxf(h0, 0.01f * h0) * wv.x;
                s += fmaxf(h1, 0.01f * h1) * wv.y;
                s += fmaxf(h2, 0.01f * h2) * wv.z;
                s += fmaxf(h3, 0.01f * h3) * wv.w;
            }
            s += __shfl_xor(s, 1);
            s += __shfl_xor(s, 2);
            s += __shfl_xor(s, 4);
            if (hq == 0)
                out[((size_t)(row0 + ph) * 16 + t) * 2 + ho] =
                    s + (ho ? blin1 : blin0);
        }
    }
}

// ---------------------------------------------------------------------------
extern "C" void kernel_launch(void* const* d_in, const int* in_sizes, int n_in,
                              void* d_out, int out_size, void* d_ws, size_t ws_size,
                              hipStream_t stream)
{
    const float* x    = (const float*)d_in[0];
    const float* hx   = (const float*)d_in[1];
    const float* cx   = (const float*)d_in[2];
    const float* Wih  = (const float*)d_in[3];
    const float* Whh  = (const float*)d_in[4];
    const float* bih  = (const float*)d_in[5];
    const float* bhh  = (const float*)d_in[6];
    const float* Wlin = (const float*)d_in[7];
    const float* blin = (const float*)d_in[8];
    float* out = (float*)d_out;

    half_t* wih_s = (half_t*)d_ws;             // 512 KB
    half_t* whh_s = wih_s + 1024 * 256;        // 512 KB

    shuffle_w_kernel<<<512, 64, 0, stream>>>(Wih, wih_s);
    shuffle_w_kernel<<<512, 64, 0, stream>>>(Whh, whh_s);
    lstm_kernel<<<200, 1024, 0, stream>>>(x, hx, cx, bih, bhh, Wlin, blin,
                                          wih_s, whh_s, out);
}

// Round 18
// 239.093 us; speedup vs baseline: 1.1416x; 1.1416x over previous
//
#include <hip/hip_runtime.h>
#include <stdint.h>
#include <stddef.h>

// ---------- types ----------
typedef _Float16 half_t;
typedef half_t half8  __attribute__((ext_vector_type(8)));
typedef half_t half4v __attribute__((ext_vector_type(4)));
typedef float  f32x4  __attribute__((ext_vector_type(4)));

__device__ __forceinline__ float fast_sigmoid(float x) {
    float e = __builtin_amdgcn_exp2f(-1.44269504f * x);
    return __builtin_amdgcn_rcpf(1.0f + e);
}
__device__ __forceinline__ float fast_tanh(float x) {
    float e = __builtin_amdgcn_exp2f(2.88539008f * x);
    return 1.0f - 2.0f * __builtin_amdgcn_rcpf(1.0f + e);
}

// ---------------------------------------------------------------------------
// Prep: W [1024][256] f32 row-major -> wave-window-contiguous MFMA-B order.
// Tile T = g*16 + w*2 + j (gate g, wave w, sub-tile j). Slot v = g*2 + j.
// Element addr: (((w*8 + kt)*8 + v)*64 + l)*8 + e  -- so the 8 fragments a
// wave needs in window kt are one contiguous 8 KB run (2 imm-offset bases).
// Value: B[k = kt*32 + (l>>4)*8 + e, col = T*16 + (l&15)] -- same
// (lane-group,elem)->k bijection as the LDS A-fragments (validated R1-R17,
// absmax 2e-3).
// ---------------------------------------------------------------------------
__global__ __launch_bounds__(64) void shuffle_w_kernel(
    const float* __restrict__ W, half_t* __restrict__ out)
{
    const int blk = blockIdx.x;         // 512 = 64 T * 8 kt
    const int T = blk >> 3, kt = blk & 7;
    const int l = threadIdx.x;
    const int w = (T & 15) >> 1, j = T & 1, g = T >> 4;
    const int v = g * 2 + j;
    const int col = T * 16 + (l & 15);
    const int k0 = kt * 32 + ((l >> 4) << 3);
    half8 vv;
#pragma unroll
    for (int e = 0; e < 8; ++e) vv[e] = (half_t)W[col * 256 + k0 + e];
    *reinterpret_cast<half8*>(
        out + ((size_t)((w * 8 + kt) * 8 + v) * 64 + l) * 8) = vv;
}

// ---------------------------------------------------------------------------
// SINGLE-PASS 4-gate GEMM: acc[mt*8 + v] (v = g*2+j) += hx @ W^T, all 4
// gates at once (acc = 32 f32x4 = the full 128-AGPR half). kt windows
// PINNED (unroll 1 + sched_barrier) -- R4-R17 proven anti-hoist. Per window:
// 8 contiguous b-frags (2 bases, imm offsets), 4 a-frags, 32 MFMA, cowork.
// R7/R8 spilled this geometry WITHOUT the toolkit (unchunked init + LICM);
// in-window arch ledger now: cxr 32 + b 32 + a 16 + head 12 + addr ~15 =
// ~107-115 <= 128.
// ---------------------------------------------------------------------------
template <typename CoWork>
__device__ __forceinline__ void gemm_all(
    f32x4* acc, const half_t* __restrict__ lhx,
    const half_t* Ws, int w, int lm, int lg, int l, CoWork&& cowork)
{
    asm volatile("" : "+v"(Ws));   // anti-LICM: recompute bases per call
    const half_t* wb = Ws + (size_t)w * 32768 + l * 8;
#pragma unroll 1
    for (int kt = 0; kt < 8; ++kt) {
        const half_t* q0 = wb + kt * 4096;
        const half_t* q1 = q0 + 2048;
        half8 b[8];
#pragma unroll
        for (int v = 0; v < 4; ++v) {
            b[v]     = *reinterpret_cast<const half8*>(q0 + v * 512);
            b[4 + v] = *reinterpret_cast<const half8*>(q1 + v * 512);
        }
        half8 a[4];
#pragma unroll
        for (int mt = 0; mt < 4; ++mt) {
            const int p = mt * 16 + lm;
            const int k = (kt * 32 + lg * 8) ^ ((p & 7) << 4);
            a[mt] = *reinterpret_cast<const half8*>(&lhx[p * 256 + k]);
        }
#pragma unroll
        for (int v = 0; v < 8; ++v)
#pragma unroll
            for (int mt = 0; mt < 4; ++mt)
                acc[mt * 8 + v] = __builtin_amdgcn_mfma_f32_16x16x32_f16(
                    a[mt], b[v], acc[mt * 8 + v], 0, 0, 0);
        cowork(kt);               // VALU work in the MFMA shadow
        __builtin_amdgcn_sched_barrier(0);   // window boundary (anti-hoist)
    }
}

// ---------------------------------------------------------------------------
// Persistent LSTM: block = 64 rows x 16 steps, 8 waves (512 threads),
// 1 blk/CU, 2 waves/SIMD (R16 geometry -- 16-wave blocks spill, 3x proven).
// R18: ONE gemm pass per step (all 4 gates) -> halves LDS A-reads, kills
// epiA + og round-trip + one fence boundary. Head(t-1) co-worked into the
// gemm windows (R16-proven, ~12 arch regs). Epilogue fully thread-local.
// LDS: hx 32 KB (XOR-swizzled) + xp 128 KB = 160 KB.
// ---------------------------------------------------------------------------
__global__ __launch_bounds__(512)
void lstm_kernel(
    const float* __restrict__ x,      // [8][256][1600]
    const float* __restrict__ hx0,    // [12800][256]
    const float* __restrict__ cx0,    // [12800][256]
    const float* __restrict__ b_ih,   // [1024]
    const float* __restrict__ b_hh,   // [1024]
    const float* __restrict__ W_lin,  // [2][256]
    const float* __restrict__ b_lin,  // [2]
    const half_t* __restrict__ Wih_s, // shuffled f16
    const half_t* __restrict__ Whh_s, // shuffled f16
    float* __restrict__ out)          // [12800][16][2]
{
    __shared__ __align__(16) half_t lds_hx[64 * 256];        // 32 KB
    __shared__ __align__(16) half_t lds_xp[8 * 32 * 64 * 4]; // 128 KB

    const int tid = threadIdx.x;
    const int w  = tid >> 6;   // wave 0..7 owns h-cols [w*32, w*32+32)
    const int l  = tid & 63;
    const int lm = l & 15;
    const int lg = l >> 4;
    const int w2 = w * 2;

    const int row0 = blockIdx.x * 64;     // 200 blocks * 64 rows
    const int bb_  = row0 / 1600;
    const int p0   = row0 % 1600;

    // ---- stage x tile into lds_hx, f16 swizzled (coalesced on p) ----
    {
        const float* xin = x + (size_t)bb_ * 409600 + p0;   // x[b][c][p0+p]
        for (int it = 0; it < 32; ++it) {
            int idx = it * 512 + tid;
            int p = idx & 63, c = idx >> 6;
            lds_hx[p * 256 + (c ^ ((p & 7) << 4))] = (half_t)xin[c * 1600 + p];
        }
    }
    __syncthreads();

    f32x4 acc[32];
    auto nocw = [](int) {};

    // ---------------- phase 0: x_proj = x @ W_ih^T + b_ih + b_hh ----------
#pragma unroll
    for (int g = 0; g < 4; ++g)
#pragma unroll
        for (int j = 0; j < 2; ++j) {
            int col = (g * 16 + w2 + j) * 16 + lm;
            float bias = b_ih[col] + b_hh[col];
#pragma unroll
            for (int mt = 0; mt < 4; ++mt)
                acc[mt * 8 + g * 2 + j] = (f32x4){bias, bias, bias, bias};
        }
    gemm_all(acc, lds_hx, Wih_s, w, lm, lg, l, nocw);

    // dump x_proj to own-wave LDS region as f16 (read back identically)
#pragma unroll
    for (int f = 0; f < 32; ++f) {
        half4v xv;
#pragma unroll
        for (int r = 0; r < 4; ++r) xv[r] = (half_t)acc[f][r];
        *reinterpret_cast<half4v*>(&lds_xp[((w * 32 + f) * 64 + l) * 4]) = xv;
    }
    __syncthreads();   // x tile fully consumed, xp written

    // ---- stage h0 into lds_hx (coalesced on c); cx into registers ----
    {
        const float* hin = hx0 + (size_t)row0 * 256;
        for (int it = 0; it < 32; ++it) {
            int idx = it * 512 + tid;
            int c = idx & 255, p = idx >> 8;
            lds_hx[p * 256 + (c ^ ((p & 7) << 4))] = (half_t)hin[p * 256 + c];
        }
    }
    float cxr[32];
#pragma unroll
    for (int mt = 0; mt < 4; ++mt)
#pragma unroll
        for (int j = 0; j < 2; ++j)
#pragma unroll
            for (int r = 0; r < 4; ++r) {
                int p = mt * 16 + lg * 4 + r;
                int c = w * 32 + j * 16 + lm;
                cxr[(mt * 2 + j) * 4 + r] = cx0[(size_t)(row0 + p) * 256 + c];
            }
    const float blin0 = b_lin[0], blin1 = b_lin[1];
    const int ph = tid >> 3;          // head: row 0..63
    const int ho = (tid >> 2) & 1;    // head: output 0..1
    const int hq = tid & 3;           // head: quarter of 256 h-cols
    __syncthreads();

    // ---------------- 16 recurrent steps ----------------
#pragma unroll 1
    for (int t = 0; t < 16; ++t) {
        // head(t-1) state: W_lin float4s pipelined one window ahead (R16)
        const float* wl = W_lin + ho * 256 + hq * 64;
        asm volatile("" : "+v"(wl));
        float hs = 0.0f;
        float4 hwv0, hwv1;
        if (t > 0) {
            hwv0 = *reinterpret_cast<const float4*>(wl + 0);
            hwv1 = *reinterpret_cast<const float4*>(wl + 4);
        }
        auto head_cw = [&](int wi) {
            if (t > 0) {
#pragma unroll
                for (int ii = 0; ii < 2; ++ii) {
                    int cb = wi * 2 + ii;
                    int c0 = hq * 64 + cb * 4;
                    half4v u = *reinterpret_cast<const half4v*>(
                        &lds_hx[ph * 256 + (c0 ^ ((ph & 7) << 4))]);
                    float4 wv = ii ? hwv1 : hwv0;
                    if (cb + 2 < 16) {   // prefetch next window's float4
                        float4 nx = *reinterpret_cast<const float4*>(
                            wl + (cb + 2) * 4);
                        if (ii) hwv1 = nx; else hwv0 = nx;
                    }
                    float h0 = (float)u[0], h1 = (float)u[1];
                    float h2 = (float)u[2], h3 = (float)u[3];
                    hs += fmaxf(h0, 0.01f * h0) * wv.x;
                    hs += fmaxf(h1, 0.01f * h1) * wv.y;
                    hs += fmaxf(h2, 0.01f * h2) * wv.z;
                    hs += fmaxf(h3, 0.01f * h3) * wv.w;
                }
            }
        };

        // acc init = x_proj, CHUNKED 4-frags-per-fence (R14-proven)
#pragma unroll
        for (int fc = 0; fc < 32; fc += 4) {
#pragma unroll
            for (int f = fc; f < fc + 4; ++f) {
                half4v u = *reinterpret_cast<const half4v*>(
                    &lds_xp[((w * 32 + f) * 64 + l) * 4]);
#pragma unroll
                for (int r = 0; r < 4; ++r) acc[f][r] = (float)u[r];
            }
            __builtin_amdgcn_sched_barrier(0);
        }

        // single GEMM pass: all 4 gates; head(t-1) in the MFMA shadow
        gemm_all(acc, lds_hx, Whh_s, w, lm, lg, l, head_cw);
        if (t > 0) {
            hs += __shfl_xor(hs, 1);
            hs += __shfl_xor(hs, 2);
            if (hq == 0)
                out[((size_t)(row0 + ph) * 16 + (t - 1)) * 2 + ho] =
                    hs + (ho ? blin1 : blin0);
        }

        __syncthreads();   // all waves finished reading lds_hx(t)

        // epilogue: full cell update (all 4 gates local); write hx(t+1)
#pragma unroll
        for (int mt = 0; mt < 4; ++mt)
#pragma unroll
            for (int j = 0; j < 2; ++j)
#pragma unroll
                for (int r = 0; r < 4; ++r) {
                    const int ci = (mt * 2 + j) * 4 + r;
                    float iv = acc[mt * 8 + 0 + j][r];
                    float fv = acc[mt * 8 + 2 + j][r];
                    float gv = acc[mt * 8 + 4 + j][r];
                    float ov = acc[mt * 8 + 6 + j][r];
                    float cxn = fast_sigmoid(fv) * cxr[ci] +
                                fast_sigmoid(iv) * fast_tanh(gv);
                    cxr[ci] = cxn;
                    float h = fast_sigmoid(ov) * fast_tanh(cxn);
                    int p  = mt * 16 + lg * 4 + r;
                    int cc = w * 32 + j * 16 + lm;
                    lds_hx[p * 256 + (cc ^ ((p & 7) << 4))] = (half_t)h;
                }
        __syncthreads();   // hx(t+1) visible to all (next gemm + head)
    }

    // ---- final head (t = 15) ----
    {
        const float* wl = W_lin + ho * 256 + hq * 64;
        asm volatile("" : "+v"(wl));
        float s = 0.0f;
#pragma unroll 2
        for (int cb = 0; cb < 16; ++cb) {
            int c0 = hq * 64 + cb * 4;
            half4v u = *reinterpret_cast<const half4v*>(
                &lds_hx[ph * 256 + (c0 ^ ((ph & 7) << 4))]);
            float4 wv = *reinterpret_cast<const float4*>(wl + cb * 4);
            float h0 = (float)u[0], h1 = (float)u[1];
            float h2 = (float)u[2], h3 = (float)u[3];
            s += fmaxf(h0, 0.01f * h0) * wv.x;
            s += fmaxf(h1, 0.01f * h1) * wv.y;
            s += fmaxf(h2, 0.01f * h2) * wv.z;
            s += fmaxf(h3, 0.01f * h3) * wv.w;
        }
        s += __shfl_xor(s, 1);
        s += __shfl_xor(s, 2);
        if (hq == 0)
            out[((size_t)(row0 + ph) * 16 + 15) * 2 + ho] =
                s + (ho ? blin1 : blin0);
    }
}

// ---------------------------------------------------------------------------
extern "C" void kernel_launch(void* const* d_in, const int* in_sizes, int n_in,
                              void* d_out, int out_size, void* d_ws, size_t ws_size,
                              hipStream_t stream)
{
    const float* x    = (const float*)d_in[0];
    const float* hx   = (const float*)d_in[1];
    const float* cx   = (const float*)d_in[2];
    const float* Wih  = (const float*)d_in[3];
    const float* Whh  = (const float*)d_in[4];
    const float* bih  = (const float*)d_in[5];
    const float* bhh  = (const float*)d_in[6];
    const float* Wlin = (const float*)d_in[7];
    const float* blin = (const float*)d_in[8];
    float* out = (float*)d_out;

    half_t* wih_s = (half_t*)d_ws;             // 512 KB
    half_t* whh_s = wih_s + 1024 * 256;        // 512 KB

    shuffle_w_kernel<<<512, 64, 0, stream>>>(Wih, wih_s);
    shuffle_w_kernel<<<512, 64, 0, stream>>>(Whh, whh_s);
    lstm_kernel<<<200, 512, 0, stream>>>(x, hx, cx, bih, bhh, Wlin, blin,
                                         wih_s, whh_s, out);
}